// Round 1
// baseline (557.872 us; speedup 1.0000x reference)
//
#include <hip/hip_runtime.h>
#include <hip/hip_cooperative_groups.h>
#include <cstddef>
#include <cstdint>

// B=4096, IN=1024, F=512, HID=128, D=128, RH=64, OUT=1, C=10, R=16
//
// out[r,b] = x[b,:]·Wfin[r,:] + bfin[r]
//   Weff[r,f] = sum_{c,h,d} w[r,c] W2[r,h] rv[r,d] fc1_w[c,h*512+f,d]
//             + sum_{c,h}   w[r,c] W2[r,h] fc1_b[c,h*512+f]
//   Wfin[r,i] = sum_f Weff[r,f] base_w[f,i]
//   bfin[r]   = sum_f Weff[r,f] base_b[f] + b1/b2 terms via hyper linearity

// ws float offsets
#define WS_WT    0        // 160    wT[c*16+r]
#define WS_RV    160      // 2048   rv[r*128+d]
#define WS_W2T   2208     // 2048   W2T[h*16+r]
#define WS_WEFF  4256     // 8192   Weff[r*512+f]
#define WS_WFIN  12448    // 16384  Wfin[r*1024+i]
#define WS_BFIN  28832    // 16
#define WS_ZERO_BEG WS_RV
#define WS_ZERO_CNT (WS_BFIN + 16 - WS_RV)   // 28688 floats (legacy path)

namespace cg = cooperative_groups;

// ---------------- front-MLP (flat-pointer version for mega-kernel) ----------------
__device__ __forceinline__ void front_mlp_flat(const float* __restrict__ pref,
                                               const float* __restrict__ wm1_w,
                                               const float* __restrict__ wm1_b,
                                               const float* __restrict__ wm2_w,
                                               const float* __restrict__ wm2_b,
                                               float* sh1, float* sw, float* sinv) {
  const int t = threadIdx.x;
  {
    int r = t >> 4, j = t & 15;
    float v = pref[r * 2 + 0] * wm1_w[j * 2 + 0] + pref[r * 2 + 1] * wm1_w[j * 2 + 1] + wm1_b[j];
    sh1[r * 16 + j] = fmaxf(v, 0.f);
  }
  __syncthreads();
  if (t < 160) {
    int r = t / 10, c = t % 10;
    float z = wm2_b[c];
    for (int j = 0; j < 16; ++j) z += sh1[r * 16 + j] * wm2_w[c * 16 + j];
    sw[r * 10 + c] = 1.f / (1.f + expf(-z));
  }
  __syncthreads();
  if (t < 16) {
    float s = 0.f;
    for (int c = 0; c < 10; ++c) s += sw[t * 10 + c];
    sinv[t] = 1.f / s;
  }
  __syncthreads();
  if (t < 160) {
    int r = t / 10, c = t % 10;
    sw[r * 10 + c] = sw[r * 10 + c] * sinv[r];
  }
  __syncthreads();
}

// =====================================================================
// Mega-kernel: all 6 stages in ONE cooperative dispatch, grid.sync()
// between dependent phases. 512 blocks x 256 thr, 64KB LDS -> exactly
// 2 blocks/CU co-resident; launch_bounds(256,2) -> 256-VGPR budget so
// the depth-8 stream pipeline cannot spill.
// =====================================================================
__global__ __launch_bounds__(256, 2) void k_all(
    const float* __restrict__ x, const float* __restrict__ pref,
    const float* __restrict__ base_w, const float* __restrict__ base_b,
    const float* __restrict__ wm1_w, const float* __restrict__ wm1_b,
    const float* __restrict__ wm2_w, const float* __restrict__ wm2_b,
    const float* __restrict__ ray0_w, const float* __restrict__ ray0_b,
    const float* __restrict__ ray2_w, const float* __restrict__ ray2_b,
    const float* __restrict__ fc1_w, const float* __restrict__ fc1_b,
    const float* __restrict__ b1_w, const float* __restrict__ b1_b,
    const float* __restrict__ fc2_w, const float* __restrict__ fc2_b,
    const float* __restrict__ b2_w, const float* __restrict__ b2_b,
    float* __restrict__ ws, float* __restrict__ out) {
  __shared__ float4 sm4[4096];          // 64 KB union across phases
  float* smf = (float*)sm4;
  cg::grid_group grid = cg::this_grid();
  const int t = threadIdx.x;
  const int blk = blockIdx.x;
  const int gid = blk * 256 + t;

  // ---------------- P0: zero accumulators (replaces hipMemsetAsync) ----------------
  // RV(2048)+W2T(2048)+WEFF(8192) contiguous at [WS_RV, WS_RV+12288); BFIN 16.
  // WFIN is fully overwritten in P4 (single-writer) -> no zero needed.
  if (gid < 12288) ws[WS_RV + gid] = 0.f;
  else if (gid < 12304) ws[WS_BFIN + (gid - 12288)] = 0.f;
  grid.sync();

  // ---------------- P1 (= k_stage1): rv, WT, W2T-bias ----------------
  if (blk < 80) {
    float* sh1  = smf;          // 256
    float* sw   = smf + 256;    // 160
    float* sinv = smf + 416;    // 16
    float* r1s  = smf + 432;    // 16*65 = 1040
    front_mlp_flat(pref, wm1_w, wm1_b, wm2_w, wm2_b, sh1, sw, sinv);
    for (int it = t; it < 1024; it += 256) {
      int r = it >> 6, o = it & 63;
      float m0 = 0.f, m1 = 0.f, rb = 0.f;
      for (int c = 0; c < 10; ++c) {
        float wv = sw[r * 10 + c];
        m0 += wv * ray0_w[(c * 64 + o) * 2 + 0];
        m1 += wv * ray0_w[(c * 64 + o) * 2 + 1];
        rb += wv * ray0_b[c * 64 + o];
      }
      float v = pref[r * 2 + 0] * m0 + pref[r * 2 + 1] * m1 + rb;
      r1s[r * 65 + o] = fmaxf(v, 0.f);
    }
    __syncthreads();
    const int pair = blk * 16 + (t >> 4);
    const int r = t & 15;
    const float* row = ray2_w + (size_t)pair * 64;
    const float* r1r = r1s + r * 65;
    float dot = 0.f;
#pragma unroll
    for (int k = 0; k < 64; ++k) dot += row[k] * r1r[k];
    int c = pair >> 7, d = pair & 127;
    atomicAdd(&ws[WS_RV + r * 128 + d], sw[r * 10 + c] * dot);

    if (blk == 0) {
      if (t < 160) ws[WS_WT + t] = sw[(t & 15) * 10 + (t >> 4)];  // WT[c*16+r]
      for (int i = t; i < 2048; i += 256) {
        int rr = i >> 7, dd = i & 127;
        float s = 0.f;
        for (int cc = 0; cc < 10; ++cc) s += sw[rr * 10 + cc] * ray2_b[cc * 128 + dd];
        atomicAdd(&ws[WS_RV + i], s);
      }
    } else if (blk == 1) {
      for (int i = t; i < 2048; i += 256) {
        int h = i >> 4, rr = i & 15;
        float s = 0.f;
        for (int cc = 0; cc < 10; ++cc) s += sw[rr * 10 + cc] * fc2_b[cc * 128 + h];
        atomicAdd(&ws[WS_W2T + i], s);
      }
    }
  }
  grid.sync();

  // ---------------- P2 (= k_stage2): W2T += w*(fc2_w·rv); 1 row per wave ----------------
  {
    const int wid = t >> 6, lane = t & 63;
    const int rid = blk * 4 + wid;                  // 0..2047, active < 1280
    if (rid < 1280) {
      float2 rvl[16];
#pragma unroll
      for (int r = 0; r < 16; ++r) rvl[r] = *(const float2*)&ws[WS_RV + r * 128 + lane * 2];
      float2 a = *(const float2*)&fc2_w[(size_t)rid * 128 + lane * 2];
      float u[16];
#pragma unroll
      for (int r = 0; r < 16; ++r) u[r] = a.x * rvl[r].x + a.y * rvl[r].y;
#pragma unroll
      for (int m = 1; m <= 32; m <<= 1) {
#pragma unroll
        for (int r = 0; r < 16; ++r) u[r] += __shfl_xor(u[r], m, 64);
      }
      if (lane == 0) {
        int c = rid >> 7, h = rid & 127;
#pragma unroll
        for (int r = 0; r < 16; ++r)
          atomicAdd(&ws[WS_W2T + h * 16 + r], u[r] * ws[WS_WT + c * 16 + r]);
      }
    }
  }
  grid.sync();

  // ---------------- P3 (= k_main): stream fc1_w; extras on blocks 0..24 ----------------
  {
    float* scoef = smf;            // 2560 floats
    float* bfred = smf + 2560;     // 64 floats
    const int wid = t >> 6, lane = t & 63, l32 = lane & 31;
    const int ch0 = (blk >> 6) * 160;               // 8 chunks of 160 ch
    const int fp  = (blk & 63) * 4 + wid;           // 0..255 (f-pair)
    for (int i = t; i < 2560; i += 256) {
      int chl = i >> 4, r = i & 15;
      int ch = ch0 + chl, c = ch >> 7, h = ch & 127;
      scoef[i] = ws[WS_WT + c * 16 + r] * ws[WS_W2T + h * 16 + r];
    }
    float4 rv[16];
#pragma unroll
    for (int r = 0; r < 16; ++r) rv[r] = *(const float4*)&ws[WS_RV + r * 128 + l32 * 4];
    __syncthreads();

    float acc[16];
#pragma unroll
    for (int r = 0; r < 16; ++r) acc[r] = 0.f;

    const float4* p = (const float4*)fc1_w + (size_t)ch0 * 16384 + fp * 64 + lane;
    float4 buf[8];
#pragma unroll
    for (int j = 0; j < 8; ++j) buf[j] = p[(size_t)j * 16384];

    for (int g = 0; g < 20; ++g) {                  // 20 groups x 8 = 160 iters
#pragma unroll
      for (int k = 0; k < 8; ++k) {
        const int chl = g * 8 + k;
        float4 cur = buf[k];
        int nxt = chl + 8; if (nxt > 159) nxt = 159;
        buf[k] = p[(size_t)nxt * 16384];
        const float4* cf = (const float4*)(scoef + chl * 16);
        float4 c0 = cf[0], c1 = cf[1], c2 = cf[2], c3 = cf[3];
        float cw[16] = {c0.x, c0.y, c0.z, c0.w, c1.x, c1.y, c1.z, c1.w,
                        c2.x, c2.y, c2.z, c2.w, c3.x, c3.y, c3.z, c3.w};
#pragma unroll
        for (int r = 0; r < 16; ++r) {
          float tt = cur.x * rv[r].x + cur.y * rv[r].y + cur.z * rv[r].z + cur.w * rv[r].w;
          acc[r] = fmaf(cw[r], tt, acc[r]);
        }
      }
    }
#pragma unroll
    for (int m = 1; m <= 16; m <<= 1) {
#pragma unroll
      for (int r = 0; r < 16; ++r) acc[r] += __shfl_xor(acc[r], m, 64);
    }
    if (l32 == 0) {
      const int f = fp * 2 + (lane >> 5);
#pragma unroll
      for (int r = 0; r < 16; ++r) atomicAdd(&ws[WS_WEFF + r * 512 + f], acc[r]);
    }
    __syncthreads();   // scoef reused by extras below

    if (blk < 16) {
      // ---- B1: Weff += coef * fc1_b
      const int bb = blk;
      const int f = (bb & 1) * 256 + t;
      const int ch0b = (bb >> 1) * 160;
      for (int i = t; i < 2560; i += 256) {
        int chl = i >> 4, r = i & 15;
        int ch = ch0b + chl, c = ch >> 7, h = ch & 127;
        scoef[i] = ws[WS_WT + c * 16 + r] * ws[WS_W2T + h * 16 + r];
      }
      __syncthreads();
      float a2[16];
#pragma unroll
      for (int r = 0; r < 16; ++r) a2[r] = 0.f;
      const float* q = fc1_b + (size_t)ch0b * 512 + f;
      float b4[4];
#pragma unroll
      for (int j = 0; j < 4; ++j) b4[j] = q[(size_t)j * 512];
      for (int g = 0; g < 40; ++g) {
#pragma unroll
        for (int k = 0; k < 4; ++k) {
          const int it = g * 4 + k;
          float xv = b4[k];
          int nxt = it + 4; if (nxt > 159) nxt = 159;
          b4[k] = q[(size_t)nxt * 512];
          const float4* cf = (const float4*)(scoef + it * 16);
          float4 c0 = cf[0], c1 = cf[1], c2 = cf[2], c3 = cf[3];
          float cw[16] = {c0.x, c0.y, c0.z, c0.w, c1.x, c1.y, c1.z, c1.w,
                          c2.x, c2.y, c2.z, c2.w, c3.x, c3.y, c3.z, c3.w};
#pragma unroll
          for (int r = 0; r < 16; ++r) a2[r] = fmaf(cw[r], xv, a2[r]);
        }
      }
#pragma unroll
      for (int r = 0; r < 16; ++r) atomicAdd(&ws[WS_WEFF + r * 512 + f], a2[r]);
    } else if (blk < 24) {
      // ---- H: bfin += coef * (b1_w[ch,:]·rv)
      const int hb = blk - 16;
      const int ch0b = hb * 160;
      for (int i = t; i < 2560; i += 256) {
        int chl = i >> 4, r = i & 15;
        int ch = ch0b + chl, c = ch >> 7, h = ch & 127;
        scoef[i] = ws[WS_WT + c * 16 + r] * ws[WS_W2T + h * 16 + r];
      }
      __syncthreads();
      float2 rv2[16];
#pragma unroll
      for (int r = 0; r < 16; ++r) rv2[r] = *(const float2*)&ws[WS_RV + r * 128 + lane * 2];
      float a2[16];
#pragma unroll
      for (int r = 0; r < 16; ++r) a2[r] = 0.f;
      const int chl0 = wid * 40;
      const float2* q = (const float2*)b1_w + (size_t)(ch0b + chl0) * 64 + lane;
      float2 b2buf[4];
#pragma unroll
      for (int j = 0; j < 4; ++j) b2buf[j] = q[(size_t)j * 64];
      for (int g = 0; g < 10; ++g) {
#pragma unroll
        for (int k = 0; k < 4; ++k) {
          const int it = g * 4 + k;
          float2 cur = b2buf[k];
          int nxt = it + 4; if (nxt > 39) nxt = 39;
          b2buf[k] = q[(size_t)nxt * 64];
          const float4* cf = (const float4*)(scoef + (chl0 + it) * 16);
          float4 c0 = cf[0], c1 = cf[1], c2 = cf[2], c3 = cf[3];
          float cw[16] = {c0.x, c0.y, c0.z, c0.w, c1.x, c1.y, c1.z, c1.w,
                          c2.x, c2.y, c2.z, c2.w, c3.x, c3.y, c3.z, c3.w};
#pragma unroll
          for (int r = 0; r < 16; ++r)
            a2[r] = fmaf(cw[r], cur.x * rv2[r].x + cur.y * rv2[r].y, a2[r]);
        }
      }
#pragma unroll
      for (int m = 1; m <= 32; m <<= 1) {
#pragma unroll
        for (int r = 0; r < 16; ++r) a2[r] += __shfl_xor(a2[r], m, 64);
      }
      if (lane == 0) {
#pragma unroll
        for (int r = 0; r < 16; ++r) bfred[wid * 16 + r] = a2[r];
      }
      __syncthreads();
      if (t < 16)
        atomicAdd(&ws[WS_BFIN + t], bfred[t] + bfred[16 + t] + bfred[32 + t] + bfred[48 + t]);
    } else if (blk == 24) {
      // ---- small terms: coef·b1_b + (w·rv)·b2_w + w·b2_b
      float a2[16];
#pragma unroll
      for (int r = 0; r < 16; ++r) a2[r] = 0.f;
      for (int i = t; i < 1280; i += 256) {
        int c = i >> 7, h = i & 127;
        float v = b1_b[c * 128 + h];
#pragma unroll
        for (int r = 0; r < 16; ++r)
          a2[r] = fmaf(ws[WS_WT + c * 16 + r] * ws[WS_W2T + h * 16 + r], v, a2[r]);
      }
      for (int i = t; i < 1280; i += 256) {
        int c = i >> 7, d = i & 127;
        float v = b2_w[c * 128 + d];
#pragma unroll
        for (int r = 0; r < 16; ++r)
          a2[r] = fmaf(ws[WS_WT + c * 16 + r] * ws[WS_RV + r * 128 + d], v, a2[r]);
      }
      if (t < 10) {
        float v = b2_b[t];
#pragma unroll
        for (int r = 0; r < 16; ++r) a2[r] = fmaf(ws[WS_WT + t * 16 + r], v, a2[r]);
      }
#pragma unroll
      for (int m = 1; m <= 32; m <<= 1) {
#pragma unroll
        for (int r = 0; r < 16; ++r) a2[r] += __shfl_xor(a2[r], m, 64);
      }
      if (lane == 0) {
#pragma unroll
        for (int r = 0; r < 16; ++r) bfred[wid * 16 + r] = a2[r];
      }
      __syncthreads();
      if (t < 16)
        atomicAdd(&ws[WS_BFIN + t], bfred[t] + bfred[16 + t] + bfred[32 + t] + bfred[48 + t]);
    }
  }
  grid.sync();

  // ---------------- P4 (= k_wfin): Wfin single-writer (no atomics); bias on blk 32 ----------------
  if (blk < 32) {
    const int il = t & 31, fg = t >> 5;             // 8 f-groups of 64
    const int i = blk * 32 + il;
    const float* WEFF = ws + WS_WEFF;
    float a4[16];
#pragma unroll
    for (int r = 0; r < 16; ++r) a4[r] = 0.f;
    const int f0 = fg * 64;
    for (int f = f0; f < f0 + 64; ++f) {
      float bw = base_w[(size_t)f * 1024 + i];
#pragma unroll
      for (int r = 0; r < 16; ++r) a4[r] = fmaf(WEFF[r * 512 + f], bw, a4[r]);
    }
    float* red = smf;                               // red[fg*512 + il*16 + r], 16 KB
#pragma unroll
    for (int r = 0; r < 16; ++r) red[fg * 512 + il * 16 + r] = a4[r];
    __syncthreads();
    for (int o = t; o < 512; o += 256) {
      int ir = o >> 4, r = o & 15;
      float s = 0.f;
#pragma unroll
      for (int fg2 = 0; fg2 < 8; ++fg2) s += red[fg2 * 512 + ir * 16 + r];
      ws[WS_WFIN + r * 1024 + blk * 32 + ir] = s;
    }
  } else if (blk == 32) {
    if (t < 64) {
      const float* WEFF = ws + WS_WEFF;
      float a2[16];
#pragma unroll
      for (int r = 0; r < 16; ++r) a2[r] = 0.f;
      for (int f = t; f < 512; f += 64) {
        float v = base_b[f];
#pragma unroll
        for (int r = 0; r < 16; ++r) a2[r] = fmaf(WEFF[r * 512 + f], v, a2[r]);
      }
#pragma unroll
      for (int m = 1; m <= 32; m <<= 1) {
#pragma unroll
        for (int r = 0; r < 16; ++r) a2[r] += __shfl_xor(a2[r], m, 64);
      }
      if (t == 0) {
#pragma unroll
        for (int r = 0; r < 16; ++r) atomicAdd(&ws[WS_BFIN + r], a2[r]);
      }
    }
  }
  grid.sync();

  // ---------------- P5 (= k_out): blocks 0..255, 16 b each ----------------
  if (blk < 256) {
    float4* wfs = sm4;                              // 64 KB: Wfin as [r*256 + i4]
    const float4* wf4 = (const float4*)(ws + WS_WFIN);
#pragma unroll
    for (int k = 0; k < 16; ++k) wfs[t + 256 * k] = wf4[t + 256 * k];
    __syncthreads();

    const int b0 = blk * 16;
    const int bp = t >> 5;
    const int isub = t & 31;
    const int bA = b0 + bp * 2;
    const float* xa = x + (size_t)bA * 1024;
    const float* xb = xa + 1024;
    float acc0[16], acc1[16];
#pragma unroll
    for (int r = 0; r < 16; ++r) { acc0[r] = 0.f; acc1[r] = 0.f; }

    for (int chunk = 0; chunk < 4; ++chunk) {
#pragma unroll
      for (int j = 0; j < 2; ++j) {
        const int off = chunk * 256 + j * 128 + isub * 4;
        float4 xv0 = *(const float4*)&xa[off];
        float4 xv1 = *(const float4*)&xb[off];
        const float4* wrow = wfs + chunk * 64 + j * 32 + isub;
#pragma unroll
        for (int r = 0; r < 16; ++r) {
          float4 w = wrow[r * 256];
          acc0[r] += xv0.x * w.x + xv0.y * w.y + xv0.z * w.z + xv0.w * w.w;
          acc1[r] += xv1.x * w.x + xv1.y * w.y + xv1.z * w.z + xv1.w * w.w;
        }
      }
    }
#pragma unroll
    for (int m = 1; m <= 16; m <<= 1) {
#pragma unroll
      for (int r = 0; r < 16; ++r) {
        acc0[r] += __shfl_xor(acc0[r], m, 64);
        acc1[r] += __shfl_xor(acc1[r], m, 64);
      }
    }
    if (isub == 0) {
#pragma unroll
      for (int r = 0; r < 16; ++r) {
        float bf = ws[WS_BFIN + r];
        float v0 = acc0[r] + bf;
        float v1 = acc1[r] + bf;
        out[r * 4096 + bA] = 1.f / (1.f + expf(-v0));
        out[r * 4096 + bA + 1] = 1.f / (1.f + expf(-v1));
        out[65536 + r * 4096 + bA] = v0;
        out[65536 + r * 4096 + bA + 1] = v1;
      }
    }
  }
}

// =====================================================================
// Legacy 6-dispatch path (proven at 557 us) — runtime fallback only.
// =====================================================================
__device__ __forceinline__ void front_mlp(const float* __restrict__ pref,
                                          const float* __restrict__ wm1_w,
                                          const float* __restrict__ wm1_b,
                                          const float* __restrict__ wm2_w,
                                          const float* __restrict__ wm2_b,
                                          float (*sh1)[16], float (*sw)[10],
                                          float* sinv) {
  const int t = threadIdx.x;
  {
    int r = t >> 4, j = t & 15;
    float v = pref[r * 2 + 0] * wm1_w[j * 2 + 0] + pref[r * 2 + 1] * wm1_w[j * 2 + 1] + wm1_b[j];
    sh1[r][j] = fmaxf(v, 0.f);
  }
  __syncthreads();
  if (t < 160) {
    int r = t / 10, c = t % 10;
    float z = wm2_b[c];
    for (int j = 0; j < 16; ++j) z += sh1[r][j] * wm2_w[c * 16 + j];
    sw[r][c] = 1.f / (1.f + expf(-z));
  }
  __syncthreads();
  if (t < 16) {
    float s = 0.f;
    for (int c = 0; c < 10; ++c) s += sw[t][c];
    sinv[t] = 1.f / s;
  }
  __syncthreads();
  if (t < 160) {
    int r = t / 10, c = t % 10;
    sw[r][c] = sw[r][c] * sinv[r];
  }
  __syncthreads();
}

__global__ __launch_bounds__(256) void k_stage1(
    const float* __restrict__ pref, const float* __restrict__ wm1_w,
    const float* __restrict__ wm1_b, const float* __restrict__ wm2_w,
    const float* __restrict__ wm2_b, const float* __restrict__ ray0_w,
    const float* __restrict__ ray0_b, const float* __restrict__ ray2_w,
    const float* __restrict__ ray2_b, const float* __restrict__ fc2_b,
    float* __restrict__ ws) {
  __shared__ float sh1[16][16];
  __shared__ float sw[16][10];
  __shared__ float sinv[16];
  __shared__ float r1s[16][65];
  const int t = threadIdx.x;
  front_mlp(pref, wm1_w, wm1_b, wm2_w, wm2_b, sh1, sw, sinv);
  for (int it = t; it < 1024; it += 256) {
    int r = it >> 6, o = it & 63;
    float m0 = 0.f, m1 = 0.f, rb = 0.f;
    for (int c = 0; c < 10; ++c) {
      float wv = sw[r][c];
      m0 += wv * ray0_w[(c * 64 + o) * 2 + 0];
      m1 += wv * ray0_w[(c * 64 + o) * 2 + 1];
      rb += wv * ray0_b[c * 64 + o];
    }
    float v = pref[r * 2 + 0] * m0 + pref[r * 2 + 1] * m1 + rb;
    r1s[r][o] = fmaxf(v, 0.f);
  }
  __syncthreads();
  const int pair = blockIdx.x * 16 + (t >> 4);
  const int r = t & 15;
  const float* row = ray2_w + (size_t)pair * 64;
  const float* r1r = r1s[r];
  float dot = 0.f;
#pragma unroll
  for (int k = 0; k < 64; ++k) dot += row[k] * r1r[k];
  int c = pair >> 7, d = pair & 127;
  atomicAdd(&ws[WS_RV + r * 128 + d], sw[r][c] * dot);

  if (blockIdx.x == 0) {
    if (t < 160) ws[WS_WT + t] = sw[t & 15][t >> 4];
    for (int i = t; i < 2048; i += 256) {
      int rr = i >> 7, dd = i & 127;
      float s = 0.f;
      for (int cc = 0; cc < 10; ++cc) s += sw[rr][cc] * ray2_b[cc * 128 + dd];
      atomicAdd(&ws[WS_RV + i], s);
    }
  } else if (blockIdx.x == 1) {
    for (int i = t; i < 2048; i += 256) {
      int h = i >> 4, rr = i & 15;
      float s = 0.f;
      for (int cc = 0; cc < 10; ++cc) s += sw[rr][cc] * fc2_b[cc * 128 + h];
      atomicAdd(&ws[WS_W2T + i], s);
    }
  }
}

__global__ __launch_bounds__(256) void k_stage2(const float* __restrict__ fc2_w,
                                                float* __restrict__ ws) {
  const int t = threadIdx.x;
  const int lane = t & 63;
  const int wv = blockIdx.x * 4 + (t >> 6);
  float2 rv2[16];
#pragma unroll
  for (int r = 0; r < 16; ++r) rv2[r] = *(const float2*)&ws[WS_RV + r * 128 + lane * 2];
  for (int q = 0; q < 4; ++q) {
    int rid = wv * 4 + q;
    int c = rid >> 7, h = rid & 127;
    float2 a = *(const float2*)&fc2_w[(size_t)rid * 128 + lane * 2];
    float u[16];
#pragma unroll
    for (int r = 0; r < 16; ++r) u[r] = a.x * rv2[r].x + a.y * rv2[r].y;
#pragma unroll
    for (int m = 1; m <= 32; m <<= 1) {
#pragma unroll
      for (int r = 0; r < 16; ++r) u[r] += __shfl_xor(u[r], m, 64);
    }
    if (lane == 0) {
#pragma unroll
      for (int r = 0; r < 16; ++r)
        atomicAdd(&ws[WS_W2T + h * 16 + r], u[r] * ws[WS_WT + c * 16 + r]);
    }
  }
}

__global__ __launch_bounds__(256, 3) void k_main(
    const float* __restrict__ fc1_w, const float* __restrict__ fc1_b,
    const float* __restrict__ b1_w, const float* __restrict__ b1_b,
    const float* __restrict__ b2_w, const float* __restrict__ b2_b,
    float* __restrict__ ws) {
  __shared__ float scoef[2560];
  __shared__ float bfred[4][16];
  const int blk = blockIdx.x;
  const int t = threadIdx.x;

  if (blk < 2048) {
    const int wid = t >> 6, lane = t & 63, l32 = lane & 31;
    const int ch0 = (blk >> 6) * 40;
    const int fp = (blk & 63) * 4 + wid;
    for (int i = t; i < 640; i += 256) {
      int chl = i >> 4, r = i & 15;
      int ch = ch0 + chl, c = ch >> 7, h = ch & 127;
      scoef[i] = ws[WS_WT + c * 16 + r] * ws[WS_W2T + h * 16 + r];
    }
    float4 rv[16];
#pragma unroll
    for (int r = 0; r < 16; ++r) rv[r] = *(const float4*)&ws[WS_RV + r * 128 + l32 * 4];
    __syncthreads();

    float acc[16];
#pragma unroll
    for (int r = 0; r < 16; ++r) acc[r] = 0.f;

    const float4* p = (const float4*)fc1_w + (size_t)ch0 * 16384 + fp * 64 + lane;

    float4 buf[8];
#pragma unroll
    for (int j = 0; j < 8; ++j) buf[j] = p[(size_t)j * 16384];

    for (int g = 0; g < 5; ++g) {
#pragma unroll
      for (int k = 0; k < 8; ++k) {
        const int chl = g * 8 + k;
        float4 cur = buf[k];
        int nxt = chl + 8; if (nxt > 39) nxt = 39;
        buf[k] = p[(size_t)nxt * 16384];
        const float4* cf = (const float4*)(scoef + chl * 16);
        float4 c0 = cf[0], c1 = cf[1], c2 = cf[2], c3 = cf[3];
        float cw[16] = {c0.x, c0.y, c0.z, c0.w, c1.x, c1.y, c1.z, c1.w,
                        c2.x, c2.y, c2.z, c2.w, c3.x, c3.y, c3.z, c3.w};
#pragma unroll
        for (int r = 0; r < 16; ++r) {
          float tt = cur.x * rv[r].x + cur.y * rv[r].y + cur.z * rv[r].z + cur.w * rv[r].w;
          acc[r] = fmaf(cw[r], tt, acc[r]);
        }
      }
    }

#pragma unroll
    for (int m = 1; m <= 16; m <<= 1) {
#pragma unroll
      for (int r = 0; r < 16; ++r) acc[r] += __shfl_xor(acc[r], m, 64);
    }
    if (l32 == 0) {
      const int f = fp * 2 + (lane >> 5);
#pragma unroll
      for (int r = 0; r < 16; ++r) atomicAdd(&ws[WS_WEFF + r * 512 + f], acc[r]);
    }
  } else if (blk < 2064) {
    const int bb = blk - 2048;
    const int f = (bb & 1) * 256 + t;
    const int ch0 = (bb >> 1) * 160;
    for (int i = t; i < 2560; i += 256) {
      int chl = i >> 4, r = i & 15;
      int ch = ch0 + chl, c = ch >> 7, h = ch & 127;
      scoef[i] = ws[WS_WT + c * 16 + r] * ws[WS_W2T + h * 16 + r];
    }
    __syncthreads();
    float acc[16];
#pragma unroll
    for (int r = 0; r < 16; ++r) acc[r] = 0.f;
    const float* q = fc1_b + (size_t)ch0 * 512 + f;
    float b4[4];
#pragma unroll
    for (int j = 0; j < 4; ++j) b4[j] = q[(size_t)j * 512];
    for (int g = 0; g < 40; ++g) {
#pragma unroll
      for (int k = 0; k < 4; ++k) {
        const int it = g * 4 + k;
        float xv = b4[k];
        int nxt = it + 4; if (nxt > 159) nxt = 159;
        b4[k] = q[(size_t)nxt * 512];
        const float4* cf = (const float4*)(scoef + it * 16);
        float4 c0 = cf[0], c1 = cf[1], c2 = cf[2], c3 = cf[3];
        float cw[16] = {c0.x, c0.y, c0.z, c0.w, c1.x, c1.y, c1.z, c1.w,
                        c2.x, c2.y, c2.z, c2.w, c3.x, c3.y, c3.z, c3.w};
#pragma unroll
        for (int r = 0; r < 16; ++r) acc[r] = fmaf(cw[r], xv, acc[r]);
      }
    }
#pragma unroll
    for (int r = 0; r < 16; ++r) atomicAdd(&ws[WS_WEFF + r * 512 + f], acc[r]);
  } else if (blk < 2072) {
    const int hb = blk - 2064;
    const int wid = t >> 6, lane = t & 63;
    const int ch0b = hb * 160;
    for (int i = t; i < 2560; i += 256) {
      int chl = i >> 4, r = i & 15;
      int ch = ch0b + chl, c = ch >> 7, h = ch & 127;
      scoef[i] = ws[WS_WT + c * 16 + r] * ws[WS_W2T + h * 16 + r];
    }
    __syncthreads();
    float2 rv2[16];
#pragma unroll
    for (int r = 0; r < 16; ++r) rv2[r] = *(const float2*)&ws[WS_RV + r * 128 + lane * 2];
    float acc[16];
#pragma unroll
    for (int r = 0; r < 16; ++r) acc[r] = 0.f;
    const int chl0 = wid * 40;
    const float2* q = (const float2*)b1_w + (size_t)(ch0b + chl0) * 64 + lane;
    float2 b2buf[4];
#pragma unroll
    for (int j = 0; j < 4; ++j) b2buf[j] = q[(size_t)j * 64];
    for (int g = 0; g < 10; ++g) {
#pragma unroll
      for (int k = 0; k < 4; ++k) {
        const int it = g * 4 + k;
        float2 cur = b2buf[k];
        int nxt = it + 4; if (nxt > 39) nxt = 39;
        b2buf[k] = q[(size_t)nxt * 64];
        const float4* cf = (const float4*)(scoef + (chl0 + it) * 16);
        float4 c0 = cf[0], c1 = cf[1], c2 = cf[2], c3 = cf[3];
        float cw[16] = {c0.x, c0.y, c0.z, c0.w, c1.x, c1.y, c1.z, c1.w,
                        c2.x, c2.y, c2.z, c2.w, c3.x, c3.y, c3.z, c3.w};
#pragma unroll
        for (int r = 0; r < 16; ++r)
          acc[r] = fmaf(cw[r], cur.x * rv2[r].x + cur.y * rv2[r].y, acc[r]);
      }
    }
#pragma unroll
    for (int m = 1; m <= 32; m <<= 1) {
#pragma unroll
      for (int r = 0; r < 16; ++r) acc[r] += __shfl_xor(acc[r], m, 64);
    }
    if (lane == 0) {
#pragma unroll
      for (int r = 0; r < 16; ++r) bfred[wid][r] = acc[r];
    }
    __syncthreads();
    if (t < 16)
      atomicAdd(&ws[WS_BFIN + t], bfred[0][t] + bfred[1][t] + bfred[2][t] + bfred[3][t]);
  } else {
    const int wid = t >> 6, lane = t & 63;
    float acc[16];
#pragma unroll
    for (int r = 0; r < 16; ++r) acc[r] = 0.f;
    for (int i = t; i < 1280; i += 256) {
      int c = i >> 7, h = i & 127;
      float v = b1_b[c * 128 + h];
#pragma unroll
      for (int r = 0; r < 16; ++r)
        acc[r] = fmaf(ws[WS_WT + c * 16 + r] * ws[WS_W2T + h * 16 + r], v, acc[r]);
    }
    for (int i = t; i < 1280; i += 256) {
      int c = i >> 7, d = i & 127;
      float v = b2_w[c * 128 + d];
#pragma unroll
      for (int r = 0; r < 16; ++r)
        acc[r] = fmaf(ws[WS_WT + c * 16 + r] * ws[WS_RV + r * 128 + d], v, acc[r]);
    }
    if (t < 10) {
      float v = b2_b[t];
#pragma unroll
      for (int r = 0; r < 16; ++r) acc[r] = fmaf(ws[WS_WT + t * 16 + r], v, acc[r]);
    }
#pragma unroll
    for (int m = 1; m <= 32; m <<= 1) {
#pragma unroll
      for (int r = 0; r < 16; ++r) acc[r] += __shfl_xor(acc[r], m, 64);
    }
    if (lane == 0) {
#pragma unroll
      for (int r = 0; r < 16; ++r) bfred[wid][r] = acc[r];
    }
    __syncthreads();
    if (t < 16)
      atomicAdd(&ws[WS_BFIN + t], bfred[0][t] + bfred[1][t] + bfred[2][t] + bfred[3][t]);
  }
}

__global__ __launch_bounds__(256) void k_wfin(const float* __restrict__ base_w,
                                              const float* __restrict__ base_b,
                                              float* __restrict__ ws) {
  const int t = threadIdx.x;
  const int blk = blockIdx.x;
  const int i = (blk & 3) * 256 + t;
  const int f0 = (blk >> 2) * 16;
  const float* WEFF = ws + WS_WEFF;
  float acc[16];
#pragma unroll
  for (int r = 0; r < 16; ++r) acc[r] = 0.f;
#pragma unroll 4
  for (int f = f0; f < f0 + 16; ++f) {
    float bw = base_w[(size_t)f * 1024 + i];
#pragma unroll
    for (int r = 0; r < 16; ++r) acc[r] = fmaf(WEFF[r * 512 + f], bw, acc[r]);
  }
#pragma unroll
  for (int r = 0; r < 16; ++r) atomicAdd(&ws[WS_WFIN + r * 1024 + i], acc[r]);

  if (blk == 0 && t < 64) {
    float a2[16];
#pragma unroll
    for (int r = 0; r < 16; ++r) a2[r] = 0.f;
    for (int f = t; f < 512; f += 64) {
      float v = base_b[f];
#pragma unroll
      for (int r = 0; r < 16; ++r) a2[r] = fmaf(WEFF[r * 512 + f], v, a2[r]);
    }
#pragma unroll
    for (int m = 1; m <= 32; m <<= 1) {
#pragma unroll
      for (int r = 0; r < 16; ++r) a2[r] += __shfl_xor(a2[r], m, 64);
    }
    if (t == 0) {
#pragma unroll
      for (int r = 0; r < 16; ++r) atomicAdd(&ws[WS_BFIN + r], a2[r]);
    }
  }
}

__global__ __launch_bounds__(256) void k_out(const float* __restrict__ x,
                                             const float* __restrict__ ws,
                                             float* __restrict__ out) {
  __shared__ float4 wfs[4096];
  const int t = threadIdx.x;
  const float4* wf4 = (const float4*)(ws + WS_WFIN);
#pragma unroll
  for (int k = 0; k < 16; ++k) wfs[t + 256 * k] = wf4[t + 256 * k];
  __syncthreads();

  const int b0 = blockIdx.x * 16;
  const int bp = t >> 5;
  const int isub = t & 31;
  const int bA = b0 + bp * 2;
  const float* xa = x + (size_t)bA * 1024;
  const float* xb = xa + 1024;
  float acc0[16], acc1[16];
#pragma unroll
  for (int r = 0; r < 16; ++r) { acc0[r] = 0.f; acc1[r] = 0.f; }

  for (int chunk = 0; chunk < 4; ++chunk) {
#pragma unroll
    for (int j = 0; j < 2; ++j) {
      const int off = chunk * 256 + j * 128 + isub * 4;
      float4 xv0 = *(const float4*)&xa[off];
      float4 xv1 = *(const float4*)&xb[off];
      const float4* wrow = wfs + chunk * 64 + j * 32 + isub;
#pragma unroll
      for (int r = 0; r < 16; ++r) {
        float4 w = wrow[r * 256];
        acc0[r] += xv0.x * w.x + xv0.y * w.y + xv0.z * w.z + xv0.w * w.w;
        acc1[r] += xv1.x * w.x + xv1.y * w.y + xv1.z * w.z + xv1.w * w.w;
      }
    }
  }
#pragma unroll
  for (int m = 1; m <= 16; m <<= 1) {
#pragma unroll
    for (int r = 0; r < 16; ++r) {
      acc0[r] += __shfl_xor(acc0[r], m, 64);
      acc1[r] += __shfl_xor(acc1[r], m, 64);
    }
  }
  if (isub == 0) {
#pragma unroll
    for (int r = 0; r < 16; ++r) {
      float bf = ws[WS_BFIN + r];
      float v0 = acc0[r] + bf;
      float v1 = acc1[r] + bf;
      out[r * 4096 + bA] = 1.f / (1.f + expf(-v0));
      out[r * 4096 + bA + 1] = 1.f / (1.f + expf(-v1));
      out[65536 + r * 4096 + bA] = v0;
      out[65536 + r * 4096 + bA + 1] = v1;
    }
  }
}

extern "C" void kernel_launch(void* const* d_in, const int* in_sizes, int n_in,
                              void* d_out, int out_size, void* d_ws, size_t ws_size,
                              hipStream_t stream) {
  (void)in_sizes; (void)n_in; (void)out_size; (void)ws_size;
  const float* x      = (const float*)d_in[0];
  const float* pref   = (const float*)d_in[1];
  const float* base_w = (const float*)d_in[2];
  const float* base_b = (const float*)d_in[3];
  const float* wm1_w  = (const float*)d_in[4];
  const float* wm1_b  = (const float*)d_in[5];
  const float* wm2_w  = (const float*)d_in[6];
  const float* wm2_b  = (const float*)d_in[7];
  const float* ray0_w = (const float*)d_in[8];
  const float* ray0_b = (const float*)d_in[9];
  const float* ray2_w = (const float*)d_in[10];
  const float* ray2_b = (const float*)d_in[11];
  const float* fc1_w  = (const float*)d_in[12];
  const float* fc1_b  = (const float*)d_in[13];
  const float* b1_w   = (const float*)d_in[14];
  const float* b1_b   = (const float*)d_in[15];
  const float* fc2_w  = (const float*)d_in[16];
  const float* fc2_b  = (const float*)d_in[17];
  const float* b2_w   = (const float*)d_in[18];
  const float* b2_b   = (const float*)d_in[19];
  float* ws  = (float*)d_ws;
  float* out = (float*)d_out;

  // One-time host-side gate (pure queries; capture-safe): cooperative launch
  // needs all 512 blocks co-resident (2/CU at 64KB LDS).
  static int g_mode = -1;
  if (g_mode < 0) {
    int maxb = 0;
    hipError_t e1 = hipOccupancyMaxActiveBlocksPerMultiprocessor(&maxb, k_all, 256, 0);
    int coop = 0, dev = 0;
    (void)hipGetDevice(&dev);
    hipError_t e2 = hipDeviceGetAttribute(&coop, hipDeviceAttributeCooperativeLaunch, dev);
    g_mode = (e1 == hipSuccess && maxb >= 2 && (e2 != hipSuccess || coop != 0)) ? 1 : 0;
  }

  if (g_mode == 1) {
    void* args[] = {
        (void*)&x, (void*)&pref, (void*)&base_w, (void*)&base_b,
        (void*)&wm1_w, (void*)&wm1_b, (void*)&wm2_w, (void*)&wm2_b,
        (void*)&ray0_w, (void*)&ray0_b, (void*)&ray2_w, (void*)&ray2_b,
        (void*)&fc1_w, (void*)&fc1_b, (void*)&b1_w, (void*)&b1_b,
        (void*)&fc2_w, (void*)&fc2_b, (void*)&b2_w, (void*)&b2_b,
        (void*)&ws, (void*)&out};
    hipError_t e = hipLaunchCooperativeKernel(k_all, dim3(512), dim3(256), args, 0, stream);
    if (e == hipSuccess) return;
    g_mode = 0;  // fall through to legacy path
  }

  hipMemsetAsync(ws + WS_ZERO_BEG, 0, (size_t)WS_ZERO_CNT * sizeof(float), stream);
  k_stage1<<<80, 256, 0, stream>>>(pref, wm1_w, wm1_b, wm2_w, wm2_b,
                                   ray0_w, ray0_b, ray2_w, ray2_b, fc2_b, ws);
  k_stage2<<<80, 256, 0, stream>>>(fc2_w, ws);
  k_main<<<2073, 256, 0, stream>>>(fc1_w, fc1_b, b1_w, b1_b, b2_w, b2_b, ws);
  k_wfin<<<128, 256, 0, stream>>>(base_w, base_b, ws);
  k_out<<<256, 256, 0, stream>>>(x, ws, out);
}